// Round 8
// baseline (910.155 us; speedup 1.0000x reference)
//
#include <hip/hip_runtime.h>

typedef __attribute__((ext_vector_type(8))) __bf16 bf16x8;
typedef __attribute__((ext_vector_type(4))) float floatx4;

#define D_MODEL 1024
#define SEQ     2048
#define BATCH   2
#define NH      16
#define DK      64
#define DFF     4096
#define NTOK    (BATCH * SEQ)   // 4096

__device__ __forceinline__ float gelu_exact(float x) {
    return 0.5f * x * (1.0f + erff(x * 0.70710678118654752f));
}

// ---------------- LayerNorm: one wave per row of 1024; fp32 in, bf16 out ------------
__global__ __launch_bounds__(64) void ln_kernel(const float* __restrict__ x,
                                                const float* __restrict__ g,
                                                const float* __restrict__ b,
                                                __bf16* __restrict__ out) {
    int row = blockIdx.x, lane = threadIdx.x, base = lane * 16;
    const float* xr = x + (size_t)row * D_MODEL + base;
    float v[16];
    for (int j = 0; j < 4; ++j) {
        floatx4 a = *(const floatx4*)(xr + 4 * j);
        for (int i = 0; i < 4; ++i) v[4 * j + i] = a[i];
    }
    float s = 0.f, sq = 0.f;
    for (int i = 0; i < 16; ++i) { s += v[i]; sq += v[i] * v[i]; }
    for (int o = 1; o < 64; o <<= 1) { s += __shfl_xor(s, o); sq += __shfl_xor(sq, o); }
    float mu = s * (1.0f / D_MODEL);
    float var = sq * (1.0f / D_MODEL) - mu * mu;
    float rstd = rsqrtf(fmaxf(var, 0.f) + 1e-5f);

    const floatx4* gp = (const floatx4*)(g + base);
    const floatx4* bp = (const floatx4*)(b + base);
    bf16x8 o0, o1;
    for (int j = 0; j < 2; ++j) {
        floatx4 gv0 = gp[2 * j], gv1 = gp[2 * j + 1];
        floatx4 bv0 = bp[2 * j], bv1 = bp[2 * j + 1];
        for (int i = 0; i < 4; ++i) {
            float r0 = (v[8 * j + i] - mu) * rstd * gv0[i] + bv0[i];
            float r1 = (v[8 * j + 4 + i] - mu) * rstd * gv1[i] + bv1[i];
            if (j == 0) { o0[i] = (__bf16)r0; o0[4 + i] = (__bf16)r1; }
            else        { o1[i] = (__bf16)r0; o1[4 + i] = (__bf16)r1; }
        }
    }
    bf16x8* op = (bf16x8*)(out + (size_t)row * D_MODEL + base);
    op[0] = o0; op[1] = o1;
}

// ---------------- GEMM: C[M,N] = A[M,K] @ W[N,K]^T + bias (+gelu) (+res) ------------
// A bf16; W fp32 (cast to bf16 during LDS staging); bias fp32; res fp32.
// 128x128 tile, BK=32, 256 threads = 4 waves (2x2), each wave 64x64 via 4x4 MFMA tiles.
template <typename OutT, bool GELU>
__global__ __launch_bounds__(256) void gemm_btf(const __bf16* __restrict__ A,
                                                const float* __restrict__ W,
                                                const float* __restrict__ bias,
                                                const float* __restrict__ res,
                                                OutT* __restrict__ out,
                                                int M, int N, int K) {
    __shared__ __bf16 As[128][40];   // +8 pad: 80B row stride (16B aligned)
    __shared__ __bf16 Ws[128][40];

    int m0 = blockIdx.y * 128, n0 = blockIdx.x * 128;
    int t = threadIdx.x;
    int lane = t & 63, wave = t >> 6;
    int wm = (wave >> 1) * 64, wn = (wave & 1) * 64;
    int fr = lane & 15, quad = lane >> 4;
    int srow = t >> 2, scol = (t & 3) * 8;

    floatx4 acc[4][4] = {};

    const __bf16* Ab = A + (size_t)(m0 + srow) * K + scol;
    const float*  Wb = W + (size_t)(n0 + srow) * K + scol;

    for (int k0 = 0; k0 < K; k0 += 32) {
        bf16x8 a0 = *(const bf16x8*)(Ab + k0);
        bf16x8 a1 = *(const bf16x8*)(Ab + (size_t)64 * K + k0);
        floatx4 f0 = *(const floatx4*)(Wb + k0);
        floatx4 f1 = *(const floatx4*)(Wb + k0 + 4);
        floatx4 f2 = *(const floatx4*)(Wb + (size_t)64 * K + k0);
        floatx4 f3 = *(const floatx4*)(Wb + (size_t)64 * K + k0 + 4);
        bf16x8 w0, w1;
        for (int j = 0; j < 4; ++j) {
            w0[j] = (__bf16)f0[j]; w0[4 + j] = (__bf16)f1[j];
            w1[j] = (__bf16)f2[j]; w1[4 + j] = (__bf16)f3[j];
        }
        __syncthreads();
        *(bf16x8*)&As[srow][scol] = a0;
        *(bf16x8*)&As[srow + 64][scol] = a1;
        *(bf16x8*)&Ws[srow][scol] = w0;
        *(bf16x8*)&Ws[srow + 64][scol] = w1;
        __syncthreads();

        bf16x8 af[4], wf[4];
        for (int i = 0; i < 4; ++i) af[i] = *(const bf16x8*)&As[wm + i * 16 + fr][quad * 8];
        for (int i = 0; i < 4; ++i) wf[i] = *(const bf16x8*)&Ws[wn + i * 16 + fr][quad * 8];
        for (int mi = 0; mi < 4; ++mi)
            for (int ni = 0; ni < 4; ++ni)
                acc[mi][ni] = __builtin_amdgcn_mfma_f32_16x16x32_bf16(af[mi], wf[ni], acc[mi][ni], 0, 0, 0);
    }

    for (int ni = 0; ni < 4; ++ni) {
        int col = n0 + wn + ni * 16 + fr;
        float bv = bias[col];
        for (int mi = 0; mi < 4; ++mi) {
            for (int r = 0; r < 4; ++r) {
                int row = m0 + wm + mi * 16 + quad * 4 + r;
                float v = acc[mi][ni][r] + bv;
                if (GELU) v = gelu_exact(v);
                if (res) v += res[(size_t)row * N + col];
                out[(size_t)row * N + col] = (OutT)v;
            }
        }
    }
}

// ---------------- V transpose: v[b][s][h*64+d] -> vt[b][h][d][s] -------------------
__global__ __launch_bounds__(256) void transpose_v(const __bf16* __restrict__ v,
                                                   __bf16* __restrict__ vt) {
    __shared__ __bf16 tile[64][72];
    int b = blockIdx.z, h = blockIdx.y, s0 = blockIdx.x * 64;
    int t = threadIdx.x;
    int dl = (t & 7) * 8, sl = t >> 3;
    for (int p = 0; p < 2; ++p) {
        int s = sl + p * 32;
        bf16x8 val = *(const bf16x8*)(v + (size_t)(b * SEQ + s0 + s) * D_MODEL + h * DK + dl);
        *(bf16x8*)&tile[s][dl] = val;
    }
    __syncthreads();
    int sl2 = (t & 7) * 8, d = t >> 3;
    for (int p = 0; p < 2; ++p) {
        int dd = d + p * 32;
        bf16x8 val;
        for (int j = 0; j < 8; ++j) val[j] = tile[sl2 + j][dd];
        *(bf16x8*)(vt + ((size_t)(b * NH + h) * DK + dd) * SEQ + s0 + sl2) = val;
    }
}

// ---------------- Flash attention: 1 wave = 16 q-rows, 64-key tiles ----------------
__global__ __launch_bounds__(256) void attn_kernel(const __bf16* __restrict__ q,
                                                   const __bf16* __restrict__ k,
                                                   const __bf16* __restrict__ vt,
                                                   __bf16* __restrict__ ctx) {
    __shared__ __bf16 Plds[4][16][72];
    int b = blockIdx.z, h = blockIdx.y;
    int wave = threadIdx.x >> 6, lane = threadIdx.x & 63;
    int q0 = blockIdx.x * 64 + wave * 16;
    int fr = lane & 15, quad = lane >> 4;

    const __bf16* qp = q + (size_t)(b * SEQ + q0 + fr) * D_MODEL + h * DK + quad * 8;
    bf16x8 qf0 = *(const bf16x8*)qp;
    bf16x8 qf1 = *(const bf16x8*)(qp + 32);

    floatx4 o[4] = {};
    float m_i[4], l_i[4];
    for (int r = 0; r < 4; ++r) { m_i[r] = -1e30f; l_i[r] = 0.f; }

    const __bf16* kbase = k + (size_t)b * SEQ * D_MODEL + h * DK + quad * 8;
    const __bf16* vtbase = vt + (size_t)(b * NH + h) * DK * SEQ;

    for (int k0 = 0; k0 < SEQ; k0 += 64) {
        bf16x8 kf[2][4], vf[2][4];
        for (int ti = 0; ti < 4; ++ti) {
            const __bf16* kp = kbase + (size_t)(k0 + ti * 16 + fr) * D_MODEL;
            kf[0][ti] = *(const bf16x8*)kp;
            kf[1][ti] = *(const bf16x8*)(kp + 32);
            const __bf16* vp = vtbase + (size_t)(ti * 16 + fr) * SEQ + k0 + quad * 8;
            vf[0][ti] = *(const bf16x8*)vp;
            vf[1][ti] = *(const bf16x8*)(vp + 32);
        }
        floatx4 sa[4] = {};
        for (int ti = 0; ti < 4; ++ti) {
            sa[ti] = __builtin_amdgcn_mfma_f32_16x16x32_bf16(qf0, kf[0][ti], sa[ti], 0, 0, 0);
            sa[ti] = __builtin_amdgcn_mfma_f32_16x16x32_bf16(qf1, kf[1][ti], sa[ti], 0, 0, 0);
        }
        const float scale = 0.125f;
        float alpha[4];
        for (int r = 0; r < 4; ++r) {
            float mx = fmaxf(fmaxf(sa[0][r], sa[1][r]), fmaxf(sa[2][r], sa[3][r])) * scale;
            for (int off = 1; off < 16; off <<= 1) mx = fmaxf(mx, __shfl_xor(mx, off));
            float mn = fmaxf(m_i[r], mx);
            alpha[r] = __expf(fminf(m_i[r] - mn, 0.f));
            m_i[r] = mn;
            float rs = 0.f;
            for (int ti = 0; ti < 4; ++ti) {
                float p = __expf(fminf(sa[ti][r] * scale - mn, 0.f));
                rs += p;
                Plds[wave][quad * 4 + r][ti * 16 + fr] = (__bf16)p;
            }
            for (int off = 1; off < 16; off <<= 1) rs += __shfl_xor(rs, off);
            l_i[r] = l_i[r] * alpha[r] + rs;
            o[0][r] *= alpha[r]; o[1][r] *= alpha[r];
            o[2][r] *= alpha[r]; o[3][r] *= alpha[r];
        }
        __syncthreads();   // cross-lane LDS write -> read fence
        bf16x8 pa0 = *(const bf16x8*)&Plds[wave][fr][quad * 8];
        bf16x8 pa1 = *(const bf16x8*)&Plds[wave][fr][32 + quad * 8];
        __syncthreads();   // read -> next-iteration write fence
        for (int ti = 0; ti < 4; ++ti) {
            o[ti] = __builtin_amdgcn_mfma_f32_16x16x32_bf16(pa0, vf[0][ti], o[ti], 0, 0, 0);
            o[ti] = __builtin_amdgcn_mfma_f32_16x16x32_bf16(pa1, vf[1][ti], o[ti], 0, 0, 0);
        }
    }
    for (int ti = 0; ti < 4; ++ti) {
        for (int r = 0; r < 4; ++r) {
            float val = o[ti][r] / fmaxf(l_i[r], 1e-30f);
            ctx[(size_t)(b * SEQ + q0 + quad * 4 + r) * D_MODEL + h * DK + ti * 16 + fr] = (__bf16)val;
        }
    }
}

// -----------------------------------------------------------------------------------
// Inputs fp32 (proven R2-vs-R5 probe); OUTPUT fp32 (reference returns jnp.float32;
// prior rounds' bf16-writes explain the constant 7.375). Workspace 56 MiB:
//   [0,8M):   h1 -> ctx        [8,16M):  qb -> h2
//   [16,24M): kb -> ffh(lo)    [24,32M): vb -> ffh(hi)   (ffh chunk = 16 MiB)
//   [32,40M): vtb              [40,56M): x1 (fp32 trunk)
extern "C" void kernel_launch(void* const* d_in, const int* in_sizes, int n_in,
                              void* d_out, int out_size, void* d_ws, size_t ws_size,
                              hipStream_t stream) {
    const float* x   = (const float*)d_in[0];
    const float* wq  = (const float*)d_in[1];
    const float* bq  = (const float*)d_in[2];
    const float* wk  = (const float*)d_in[3];
    const float* bk  = (const float*)d_in[4];
    const float* wv  = (const float*)d_in[5];
    const float* bv  = (const float*)d_in[6];
    const float* wo  = (const float*)d_in[7];
    const float* bo  = (const float*)d_in[8];
    const float* w1  = (const float*)d_in[9];
    const float* b1  = (const float*)d_in[10];
    const float* w2  = (const float*)d_in[11];
    const float* b2  = (const float*)d_in[12];
    const float* g1  = (const float*)d_in[13];
    const float* be1 = (const float*)d_in[14];
    const float* g2  = (const float*)d_in[15];
    const float* be2 = (const float*)d_in[16];
    float* out = (float*)d_out;   // fp32 output

    char* ws = (char*)d_ws;
    const size_t MB = 1024 * 1024;
    __bf16* h1  = (__bf16*)(ws);            // [0,8M)
    __bf16* ctx = (__bf16*)(ws);            // over h1 (dead after v-proj)
    __bf16* qb  = (__bf16*)(ws + 8 * MB);
    __bf16* h2  = (__bf16*)(ws + 8 * MB);   // over qb (dead after attn)
    __bf16* kb  = (__bf16*)(ws + 16 * MB);
    __bf16* ffh = (__bf16*)(ws + 16 * MB);  // 16 MiB over kb+vb (dead after attn)
    __bf16* vb  = (__bf16*)(ws + 24 * MB);
    __bf16* vtb = (__bf16*)(ws + 32 * MB);
    float*  x1  = (float*)(ws + 40 * MB);   // [40,56M) fp32 trunk

    dim3 gD(D_MODEL / 128, NTOK / 128);   // (8, 32)
    dim3 gAttn(SEQ / 64, NH, BATCH);      // (32, 16, 2)

    // 1. h1 = LN(x, g1, be1)
    ln_kernel<<<NTOK, 64, 0, stream>>>(x, g1, be1, h1);
    // 2-4. q,k,v projections (W fp32 inline-cast)
    gemm_btf<__bf16, false><<<gD, 256, 0, stream>>>(h1, wq, bq, nullptr, qb, NTOK, D_MODEL, D_MODEL);
    gemm_btf<__bf16, false><<<gD, 256, 0, stream>>>(h1, wk, bk, nullptr, kb, NTOK, D_MODEL, D_MODEL);
    gemm_btf<__bf16, false><<<gD, 256, 0, stream>>>(h1, wv, bv, nullptr, vb, NTOK, D_MODEL, D_MODEL);
    // 5. vt = transpose(v) per head
    transpose_v<<<gAttn, 256, 0, stream>>>(vb, vtb);
    // 6. ctx = softmax(q k^T / sqrt(dk)) v   (over h1)
    attn_kernel<<<gAttn, 256, 0, stream>>>(qb, kb, vtb, ctx);
    // 7. x1 = x + ctx @ wo^T + bo   (fp32 trunk)
    gemm_btf<float, false><<<gD, 256, 0, stream>>>(ctx, wo, bo, x, x1, NTOK, D_MODEL, D_MODEL);
    // 8. h2 = LN(x1, g2, be2)   (over qb)
    ln_kernel<<<NTOK, 64, 0, stream>>>(x1, g2, be2, h2);
    // 9-10. FFN in 2 row-chunks of 2048 (ffh 16 MiB over kb+vb); final out fp32
    for (int c = 0; c < 2; ++c) {
        const __bf16* h2c = h2 + (size_t)c * 2048 * D_MODEL;
        const float*  x1c = x1 + (size_t)c * 2048 * D_MODEL;
        float* outc = out + (size_t)c * 2048 * D_MODEL;
        dim3 g1g(DFF / 128, 2048 / 128);     // (32, 16)
        dim3 g2g(D_MODEL / 128, 2048 / 128); // (8, 16)
        gemm_btf<__bf16, true><<<g1g, 256, 0, stream>>>(h2c, w1, b1, nullptr, ffh, 2048, DFF, D_MODEL);
        gemm_btf<float, false><<<g2g, 256, 0, stream>>>(ffh, w2, b2, x1c, outc, 2048, D_MODEL, DFF);
    }
}

// Round 9
// 820.872 us; speedup vs baseline: 1.1088x; 1.1088x over previous
//
#include <hip/hip_runtime.h>

typedef __attribute__((ext_vector_type(8))) __bf16 bf16x8;
typedef __attribute__((ext_vector_type(4))) float floatx4;
typedef void __attribute__((address_space(3))) lds_void_t;
typedef const void __attribute__((address_space(1))) gbl_void_t;

#define D_MODEL 1024
#define SEQ     2048
#define BATCH   2
#define NH      16
#define DK      64
#define DFF     4096
#define NTOK    (BATCH * SEQ)   // 4096

__device__ __forceinline__ float gelu_exact(float x) {
    return 0.5f * x * (1.0f + erff(x * 0.70710678118654752f));
}

// ---------------- fp32 -> bf16 weight cast, 8 elems/thread --------------------------
__global__ __launch_bounds__(256) void cast_f32_bf16(const float* __restrict__ src,
                                                     __bf16* __restrict__ dst, int n) {
    int i = (blockIdx.x * 256 + threadIdx.x) * 8;
    if (i >= n) return;
    floatx4 a = *(const floatx4*)(src + i);
    floatx4 b = *(const floatx4*)(src + i + 4);
    bf16x8 o;
    for (int j = 0; j < 4; ++j) { o[j] = (__bf16)a[j]; o[4 + j] = (__bf16)b[j]; }
    *(bf16x8*)(dst + i) = o;
}

// ---------------- LayerNorm: one wave per row of 1024; fp32 in, bf16 out ------------
__global__ __launch_bounds__(64) void ln_kernel(const float* __restrict__ x,
                                                const float* __restrict__ g,
                                                const float* __restrict__ b,
                                                __bf16* __restrict__ out) {
    int row = blockIdx.x, lane = threadIdx.x, base = lane * 16;
    const float* xr = x + (size_t)row * D_MODEL + base;
    float v[16];
    for (int j = 0; j < 4; ++j) {
        floatx4 a = *(const floatx4*)(xr + 4 * j);
        for (int i = 0; i < 4; ++i) v[4 * j + i] = a[i];
    }
    float s = 0.f, sq = 0.f;
    for (int i = 0; i < 16; ++i) { s += v[i]; sq += v[i] * v[i]; }
    for (int o = 1; o < 64; o <<= 1) { s += __shfl_xor(s, o); sq += __shfl_xor(sq, o); }
    float mu = s * (1.0f / D_MODEL);
    float var = sq * (1.0f / D_MODEL) - mu * mu;
    float rstd = rsqrtf(fmaxf(var, 0.f) + 1e-5f);

    const floatx4* gp = (const floatx4*)(g + base);
    const floatx4* bp = (const floatx4*)(b + base);
    bf16x8 o0, o1;
    for (int j = 0; j < 2; ++j) {
        floatx4 gv0 = gp[2 * j], gv1 = gp[2 * j + 1];
        floatx4 bv0 = bp[2 * j], bv1 = bp[2 * j + 1];
        for (int i = 0; i < 4; ++i) {
            float r0 = (v[8 * j + i] - mu) * rstd * gv0[i] + bv0[i];
            float r1 = (v[8 * j + 4 + i] - mu) * rstd * gv1[i] + bv1[i];
            if (j == 0) { o0[i] = (__bf16)r0; o0[4 + i] = (__bf16)r1; }
            else        { o1[i] = (__bf16)r0; o1[4 + i] = (__bf16)r1; }
        }
    }
    bf16x8* op = (bf16x8*)(out + (size_t)row * D_MODEL + base);
    op[0] = o0; op[1] = o1;
}

// ---------------- GEMM (m97-style): C = A@W^T + bias (+gelu) (+res) -----------------
// A, W bf16 K-contiguous. 128x128 tile, BK=32, 4 waves. global_load_lds width=16
// staging into unpadded [128][32] LDS (offset == 16*t matches wave_base + lane*16).
template <typename OutT, bool GELU>
__global__ __launch_bounds__(256) void gemm_bt(const __bf16* __restrict__ A,
                                               const __bf16* __restrict__ W,
                                               const float* __restrict__ bias,
                                               const float* __restrict__ res,
                                               OutT* __restrict__ out,
                                               int M, int N, int K) {
    __shared__ __bf16 As[128][32];
    __shared__ __bf16 Ws[128][32];

    int m0 = blockIdx.y * 128, n0 = blockIdx.x * 128;
    int t = threadIdx.x;
    int lane = t & 63, wave = t >> 6;
    int wm = (wave >> 1) * 64, wn = (wave & 1) * 64;
    int fr = lane & 15, quad = lane >> 4;
    int srow = t >> 2, scol = (t & 3) * 8;

    floatx4 acc[4][4] = {};

    const __bf16* Ab = A + (size_t)(m0 + srow) * K + scol;
    const __bf16* Wb = W + (size_t)(n0 + srow) * K + scol;
    lds_void_t* lA0 = (lds_void_t*)&As[wave * 16][0];
    lds_void_t* lA1 = (lds_void_t*)&As[64 + wave * 16][0];
    lds_void_t* lW0 = (lds_void_t*)&Ws[wave * 16][0];
    lds_void_t* lW1 = (lds_void_t*)&Ws[64 + wave * 16][0];

    for (int k0 = 0; k0 < K; k0 += 32) {
        __syncthreads();   // WAR: all ds_reads of prev tile done
        __builtin_amdgcn_global_load_lds((gbl_void_t*)(Ab + k0), lA0, 16, 0, 0);
        __builtin_amdgcn_global_load_lds((gbl_void_t*)(Ab + (size_t)64 * K + k0), lA1, 16, 0, 0);
        __builtin_amdgcn_global_load_lds((gbl_void_t*)(Wb + k0), lW0, 16, 0, 0);
        __builtin_amdgcn_global_load_lds((gbl_void_t*)(Wb + (size_t)64 * K + k0), lW1, 16, 0, 0);
        __syncthreads();   // includes vmcnt(0) drain -> staged data visible

        bf16x8 af[4], wf[4];
        for (int i = 0; i < 4; ++i) af[i] = *(const bf16x8*)&As[wm + i * 16 + fr][quad * 8];
        for (int i = 0; i < 4; ++i) wf[i] = *(const bf16x8*)&Ws[wn + i * 16 + fr][quad * 8];
        for (int mi = 0; mi < 4; ++mi)
            for (int ni = 0; ni < 4; ++ni)
                acc[mi][ni] = __builtin_amdgcn_mfma_f32_16x16x32_bf16(af[mi], wf[ni], acc[mi][ni], 0, 0, 0);
    }

    for (int ni = 0; ni < 4; ++ni) {
        int col = n0 + wn + ni * 16 + fr;
        float bv = bias[col];
        for (int mi = 0; mi < 4; ++mi) {
            for (int r = 0; r < 4; ++r) {
                int row = m0 + wm + mi * 16 + quad * 4 + r;
                float v = acc[mi][ni][r] + bv;
                if (GELU) v = gelu_exact(v);
                if (res) v += res[(size_t)row * N + col];
                out[(size_t)row * N + col] = (OutT)v;
            }
        }
    }
}

// ---------------- V transpose: v[b][s][h*64+d] -> vt[b][h][d][s] -------------------
__global__ __launch_bounds__(256) void transpose_v(const __bf16* __restrict__ v,
                                                   __bf16* __restrict__ vt) {
    __shared__ __bf16 tile[64][72];
    int b = blockIdx.z, h = blockIdx.y, s0 = blockIdx.x * 64;
    int t = threadIdx.x;
    int dl = (t & 7) * 8, sl = t >> 3;
    for (int p = 0; p < 2; ++p) {
        int s = sl + p * 32;
        bf16x8 val = *(const bf16x8*)(v + (size_t)(b * SEQ + s0 + s) * D_MODEL + h * DK + dl);
        *(bf16x8*)&tile[s][dl] = val;
    }
    __syncthreads();
    int sl2 = (t & 7) * 8, d = t >> 3;
    for (int p = 0; p < 2; ++p) {
        int dd = d + p * 32;
        bf16x8 val;
        for (int j = 0; j < 8; ++j) val[j] = tile[sl2 + j][dd];
        *(bf16x8*)(vt + ((size_t)(b * NH + h) * DK + dd) * SEQ + s0 + sl2) = val;
    }
}

// ---------------- Flash attention: 1 wave = 16 q-rows, 64-key tiles ----------------
// No __syncthreads: P round-trip LDS is wave-private; __threadfence_block orders
// the cross-lane ds_write -> ds_read without an inter-wave barrier convoy.
// K is register-prefetched one tile ahead (consumed at iteration top).
__global__ __launch_bounds__(256) void attn_kernel(const __bf16* __restrict__ q,
                                                   const __bf16* __restrict__ k,
                                                   const __bf16* __restrict__ vt,
                                                   __bf16* __restrict__ ctx) {
    __shared__ __bf16 Plds[4][16][72];
    int b = blockIdx.z, h = blockIdx.y;
    int wave = threadIdx.x >> 6, lane = threadIdx.x & 63;
    int q0 = blockIdx.x * 64 + wave * 16;
    int fr = lane & 15, quad = lane >> 4;

    const __bf16* qp = q + (size_t)(b * SEQ + q0 + fr) * D_MODEL + h * DK + quad * 8;
    bf16x8 qf0 = *(const bf16x8*)qp;
    bf16x8 qf1 = *(const bf16x8*)(qp + 32);

    floatx4 o[4] = {};
    float m_i[4], l_i[4];
    for (int r = 0; r < 4; ++r) { m_i[r] = -1e30f; l_i[r] = 0.f; }

    const __bf16* kbase = k + (size_t)b * SEQ * D_MODEL + h * DK + quad * 8;
    const __bf16* vtbase = vt + (size_t)(b * NH + h) * DK * SEQ;

    bf16x8 kc[2][4], kn[2][4];
    for (int ti = 0; ti < 4; ++ti) {
        const __bf16* kp = kbase + (size_t)(ti * 16 + fr) * D_MODEL;
        kc[0][ti] = *(const bf16x8*)kp;
        kc[1][ti] = *(const bf16x8*)(kp + 32);
    }

    for (int k0 = 0; k0 < SEQ; k0 += 64) {
        // V loads for current tile (consumed at end of iteration -> latency hidden)
        bf16x8 vf[2][4];
        for (int ti = 0; ti < 4; ++ti) {
            const __bf16* vp = vtbase + (size_t)(ti * 16 + fr) * SEQ + k0 + quad * 8;
            vf[0][ti] = *(const bf16x8*)vp;
            vf[1][ti] = *(const bf16x8*)(vp + 32);
        }
        // prefetch next K tile
        if (k0 + 64 < SEQ) {
            for (int ti = 0; ti < 4; ++ti) {
                const __bf16* kp = kbase + (size_t)(k0 + 64 + ti * 16 + fr) * D_MODEL;
                kn[0][ti] = *(const bf16x8*)kp;
                kn[1][ti] = *(const bf16x8*)(kp + 32);
            }
        }
        floatx4 sa[4] = {};
        for (int ti = 0; ti < 4; ++ti) {
            sa[ti] = __builtin_amdgcn_mfma_f32_16x16x32_bf16(qf0, kc[0][ti], sa[ti], 0, 0, 0);
            sa[ti] = __builtin_amdgcn_mfma_f32_16x16x32_bf16(qf1, kc[1][ti], sa[ti], 0, 0, 0);
        }
        const float scale = 0.125f;
        float alpha[4];
        for (int r = 0; r < 4; ++r) {
            float mx = fmaxf(fmaxf(sa[0][r], sa[1][r]), fmaxf(sa[2][r], sa[3][r])) * scale;
            for (int off = 1; off < 16; off <<= 1) mx = fmaxf(mx, __shfl_xor(mx, off));
            float mn = fmaxf(m_i[r], mx);
            alpha[r] = __expf(fminf(m_i[r] - mn, 0.f));
            m_i[r] = mn;
            float rs = 0.f;
            for (int ti = 0; ti < 4; ++ti) {
                float p = __expf(fminf(sa[ti][r] * scale - mn, 0.f));
                rs += p;
                Plds[wave][quad * 4 + r][ti * 16 + fr] = (__bf16)p;
            }
            for (int off = 1; off < 16; off <<= 1) rs += __shfl_xor(rs, off);
            l_i[r] = l_i[r] * alpha[r] + rs;
            o[0][r] *= alpha[r]; o[1][r] *= alpha[r];
            o[2][r] *= alpha[r]; o[3][r] *= alpha[r];
        }
        __threadfence_block();   // order wave-private LDS write -> cross-lane read
        bf16x8 pa0 = *(const bf16x8*)&Plds[wave][fr][quad * 8];
        bf16x8 pa1 = *(const bf16x8*)&Plds[wave][fr][32 + quad * 8];
        for (int ti = 0; ti < 4; ++ti) {
            o[ti] = __builtin_amdgcn_mfma_f32_16x16x32_bf16(pa0, vf[0][ti], o[ti], 0, 0, 0);
            o[ti] = __builtin_amdgcn_mfma_f32_16x16x32_bf16(pa1, vf[1][ti], o[ti], 0, 0, 0);
        }
        for (int i = 0; i < 4; ++i) { kc[0][i] = kn[0][i]; kc[1][i] = kn[1][i]; }
    }
    for (int ti = 0; ti < 4; ++ti) {
        for (int r = 0; r < 4; ++r) {
            float val = o[ti][r] / fmaxf(l_i[r], 1e-30f);
            ctx[(size_t)(b * SEQ + q0 + quad * 4 + r) * D_MODEL + h * DK + ti * 16 + fr] = (__bf16)val;
        }
    }
}

// -----------------------------------------------------------------------------------
// Inputs fp32, output fp32. Workspace 72 MiB:
//   [0,24M):  bf16 weights (wq,wk,wv,wo 2M each; w1 8M; w2 8M)  -- persist
//   [24,40M): x1 fp32 trunk
//   [40,48M): h1 -> vtb        [48,56M): qb -> h2
//   [56,64M): kb -> ffh(lo)    [64,72M): vb -> ctx -> ffh(hi)
extern "C" void kernel_launch(void* const* d_in, const int* in_sizes, int n_in,
                              void* d_out, int out_size, void* d_ws, size_t ws_size,
                              hipStream_t stream) {
    const float* x   = (const float*)d_in[0];
    const float* wq  = (const float*)d_in[1];
    const float* bq  = (const float*)d_in[2];
    const float* wk  = (const float*)d_in[3];
    const float* bk  = (const float*)d_in[4];
    const float* wv  = (const float*)d_in[5];
    const float* bv  = (const float*)d_in[6];
    const float* wo  = (const float*)d_in[7];
    const float* bo  = (const float*)d_in[8];
    const float* w1  = (const float*)d_in[9];
    const float* b1  = (const float*)d_in[10];
    const float* w2  = (const float*)d_in[11];
    const float* b2  = (const float*)d_in[12];
    const float* g1  = (const float*)d_in[13];
    const float* be1 = (const float*)d_in[14];
    const float* g2  = (const float*)d_in[15];
    const float* be2 = (const float*)d_in[16];
    float* out = (float*)d_out;

    char* ws = (char*)d_ws;
    const size_t MB = 1024 * 1024;
    __bf16* wqB = (__bf16*)(ws);
    __bf16* wkB = (__bf16*)(ws + 2 * MB);
    __bf16* wvB = (__bf16*)(ws + 4 * MB);
    __bf16* woB = (__bf16*)(ws + 6 * MB);
    __bf16* w1B = (__bf16*)(ws + 8 * MB);
    __bf16* w2B = (__bf16*)(ws + 16 * MB);
    float*  x1  = (float*)(ws + 24 * MB);
    __bf16* h1  = (__bf16*)(ws + 40 * MB);
    __bf16* vtb = (__bf16*)(ws + 40 * MB);  // over h1 (dead after v-proj)
    __bf16* qb  = (__bf16*)(ws + 48 * MB);
    __bf16* h2  = (__bf16*)(ws + 48 * MB);  // over qb (dead after attn)
    __bf16* kb  = (__bf16*)(ws + 56 * MB);
    __bf16* ffh = (__bf16*)(ws + 56 * MB);  // 16 MiB over kb+ctx (dead after wo-gemm)
    __bf16* vb  = (__bf16*)(ws + 64 * MB);
    __bf16* ctx = (__bf16*)(ws + 64 * MB);  // over vb (dead after transpose)

    const int NDD = D_MODEL * D_MODEL;   // 1M
    const int NDF = D_MODEL * DFF;       // 4M
    cast_f32_bf16<<<NDD / 2048, 256, 0, stream>>>(wq, wqB, NDD);
    cast_f32_bf16<<<NDD / 2048, 256, 0, stream>>>(wk, wkB, NDD);
    cast_f32_bf16<<<NDD / 2048, 256, 0, stream>>>(wv, wvB, NDD);
    cast_f32_bf16<<<NDD / 2048, 256, 0, stream>>>(wo, woB, NDD);
    cast_f32_bf16<<<NDF / 2048, 256, 0, stream>>>(w1, w1B, NDF);
    cast_f32_bf16<<<NDF / 2048, 256, 0, stream>>>(w2, w2B, NDF);

    dim3 gD(D_MODEL / 128, NTOK / 128);   // (8, 32)
    dim3 gAttn(SEQ / 64, NH, BATCH);      // (32, 16, 2)

    // 1. h1 = LN(x, g1, be1)
    ln_kernel<<<NTOK, 64, 0, stream>>>(x, g1, be1, h1);
    // 2-4. q,k,v projections
    gemm_bt<__bf16, false><<<gD, 256, 0, stream>>>(h1, wqB, bq, nullptr, qb, NTOK, D_MODEL, D_MODEL);
    gemm_bt<__bf16, false><<<gD, 256, 0, stream>>>(h1, wkB, bk, nullptr, kb, NTOK, D_MODEL, D_MODEL);
    gemm_bt<__bf16, false><<<gD, 256, 0, stream>>>(h1, wvB, bv, nullptr, vb, NTOK, D_MODEL, D_MODEL);
    // 5. vt = transpose(v) per head  (over h1)
    transpose_v<<<gAttn, 256, 0, stream>>>(vb, vtb);
    // 6. ctx = softmax(q k^T / sqrt(dk)) v  (over vb)
    attn_kernel<<<gAttn, 256, 0, stream>>>(qb, kb, vtb, ctx);
    // 7. x1 = x + ctx @ wo^T + bo   (fp32 trunk)
    gemm_bt<float, false><<<gD, 256, 0, stream>>>(ctx, woB, bo, x, x1, NTOK, D_MODEL, D_MODEL);
    // 8. h2 = LN(x1, g2, be2)   (over qb)
    ln_kernel<<<NTOK, 64, 0, stream>>>(x1, g2, be2, h2);
    // 9-10. FFN in 2 row-chunks of 2048 (ffh 16 MiB over kb+ctx)
    for (int c = 0; c < 2; ++c) {
        const __bf16* h2c = h2 + (size_t)c * 2048 * D_MODEL;
        const float*  x1c = x1 + (size_t)c * 2048 * D_MODEL;
        float* outc = out + (size_t)c * 2048 * D_MODEL;
        dim3 g1g(DFF / 128, 2048 / 128);     // (32, 16)
        dim3 g2g(D_MODEL / 128, 2048 / 128); // (8, 16)
        gemm_bt<__bf16, true><<<g1g, 256, 0, stream>>>(h2c, w1B, b1, nullptr, ffh, 2048, DFF, D_MODEL);
        gemm_bt<float, false><<<g2g, 256, 0, stream>>>(ffh, w2B, b2, x1c, outc, 2048, D_MODEL, DFF);
    }
}

// Round 10
// 708.157 us; speedup vs baseline: 1.2852x; 1.1592x over previous
//
#include <hip/hip_runtime.h>

typedef __attribute__((ext_vector_type(8))) __bf16 bf16x8;
typedef __attribute__((ext_vector_type(4))) __bf16 bf16x4;
typedef __attribute__((ext_vector_type(4))) float floatx4;
typedef void __attribute__((address_space(3))) lds_void_t;
typedef const void __attribute__((address_space(1))) gbl_void_t;

#define D_MODEL 1024
#define SEQ     2048
#define BATCH   2
#define NH      16
#define DK      64
#define DFF     4096
#define NTOK    (BATCH * SEQ)   // 4096
#define QKVS    3072            // fused qkv row stride

__device__ __forceinline__ float gelu_exact(float x) {
    return 0.5f * x * (1.0f + erff(x * 0.70710678118654752f));
}

// ---------------- fp32 -> bf16 weight cast, 8 elems/thread --------------------------
__global__ __launch_bounds__(256) void cast_f32_bf16(const float* __restrict__ src,
                                                     __bf16* __restrict__ dst, int n) {
    int i = (blockIdx.x * 256 + threadIdx.x) * 8;
    if (i >= n) return;
    floatx4 a = *(const floatx4*)(src + i);
    floatx4 b = *(const floatx4*)(src + i + 4);
    bf16x8 o;
    for (int j = 0; j < 4; ++j) { o[j] = (__bf16)a[j]; o[4 + j] = (__bf16)b[j]; }
    *(bf16x8*)(dst + i) = o;
}

// ---------------- LayerNorm: one wave per row of 1024; fp32 in, bf16 out ------------
__global__ __launch_bounds__(64) void ln_kernel(const float* __restrict__ x,
                                                const float* __restrict__ g,
                                                const float* __restrict__ b,
                                                __bf16* __restrict__ out) {
    int row = blockIdx.x, lane = threadIdx.x, base = lane * 16;
    const float* xr = x + (size_t)row * D_MODEL + base;
    float v[16];
    for (int j = 0; j < 4; ++j) {
        floatx4 a = *(const floatx4*)(xr + 4 * j);
        for (int i = 0; i < 4; ++i) v[4 * j + i] = a[i];
    }
    float s = 0.f, sq = 0.f;
    for (int i = 0; i < 16; ++i) { s += v[i]; sq += v[i] * v[i]; }
    for (int o = 1; o < 64; o <<= 1) { s += __shfl_xor(s, o); sq += __shfl_xor(sq, o); }
    float mu = s * (1.0f / D_MODEL);
    float var = sq * (1.0f / D_MODEL) - mu * mu;
    float rstd = rsqrtf(fmaxf(var, 0.f) + 1e-5f);

    const floatx4* gp = (const floatx4*)(g + base);
    const floatx4* bp = (const floatx4*)(b + base);
    bf16x8 o0, o1;
    for (int j = 0; j < 2; ++j) {
        floatx4 gv0 = gp[2 * j], gv1 = gp[2 * j + 1];
        floatx4 bv0 = bp[2 * j], bv1 = bp[2 * j + 1];
        for (int i = 0; i < 4; ++i) {
            float r0 = (v[8 * j + i] - mu) * rstd * gv0[i] + bv0[i];
            float r1 = (v[8 * j + 4 + i] - mu) * rstd * gv1[i] + bv1[i];
            if (j == 0) { o0[i] = (__bf16)r0; o0[4 + i] = (__bf16)r1; }
            else        { o1[i] = (__bf16)r0; o1[4 + i] = (__bf16)r1; }
        }
    }
    bf16x8* op = (bf16x8*)(out + (size_t)row * D_MODEL + base);
    op[0] = o0; op[1] = o1;
}

// ---------------- GEMM (m97-style): C = A@W^T + bias (+gelu) (+res) -----------------
// A, W bf16 K-contiguous. 128x128 tile, BK=32, 4 waves, global_load_lds width=16.
// TRIBIAS: bias segmented per 1024 cols (fused QKV).
template <typename OutT, bool GELU, bool TRIBIAS>
__global__ __launch_bounds__(256) void gemm_bt(const __bf16* __restrict__ A,
                                               const __bf16* __restrict__ W,
                                               const float* __restrict__ bias0,
                                               const float* __restrict__ bias1,
                                               const float* __restrict__ bias2,
                                               const float* __restrict__ res,
                                               OutT* __restrict__ out,
                                               int M, int N, int K) {
    __shared__ __bf16 As[128][32];
    __shared__ __bf16 Ws[128][32];

    int m0 = blockIdx.y * 128, n0 = blockIdx.x * 128;
    int t = threadIdx.x;
    int lane = t & 63, wave = t >> 6;
    int wm = (wave >> 1) * 64, wn = (wave & 1) * 64;
    int fr = lane & 15, quad = lane >> 4;
    int srow = t >> 2, scol = (t & 3) * 8;

    floatx4 acc[4][4] = {};

    const __bf16* Ab = A + (size_t)(m0 + srow) * K + scol;
    const __bf16* Wb = W + (size_t)(n0 + srow) * K + scol;
    lds_void_t* lA0 = (lds_void_t*)&As[wave * 16][0];
    lds_void_t* lA1 = (lds_void_t*)&As[64 + wave * 16][0];
    lds_void_t* lW0 = (lds_void_t*)&Ws[wave * 16][0];
    lds_void_t* lW1 = (lds_void_t*)&Ws[64 + wave * 16][0];

    for (int k0 = 0; k0 < K; k0 += 32) {
        __syncthreads();
        __builtin_amdgcn_global_load_lds((gbl_void_t*)(Ab + k0), lA0, 16, 0, 0);
        __builtin_amdgcn_global_load_lds((gbl_void_t*)(Ab + (size_t)64 * K + k0), lA1, 16, 0, 0);
        __builtin_amdgcn_global_load_lds((gbl_void_t*)(Wb + k0), lW0, 16, 0, 0);
        __builtin_amdgcn_global_load_lds((gbl_void_t*)(Wb + (size_t)64 * K + k0), lW1, 16, 0, 0);
        __syncthreads();

        bf16x8 af[4], wf[4];
        for (int i = 0; i < 4; ++i) af[i] = *(const bf16x8*)&As[wm + i * 16 + fr][quad * 8];
        for (int i = 0; i < 4; ++i) wf[i] = *(const bf16x8*)&Ws[wn + i * 16 + fr][quad * 8];
        for (int mi = 0; mi < 4; ++mi)
            for (int ni = 0; ni < 4; ++ni)
                acc[mi][ni] = __builtin_amdgcn_mfma_f32_16x16x32_bf16(af[mi], wf[ni], acc[mi][ni], 0, 0, 0);
    }

    for (int ni = 0; ni < 4; ++ni) {
        int col = n0 + wn + ni * 16 + fr;
        const float* bp = bias0;
        int bcol = col;
        if (TRIBIAS) { bp = col < 1024 ? bias0 : (col < 2048 ? bias1 : bias2); bcol = col & 1023; }
        float bv = bp[bcol];
        for (int mi = 0; mi < 4; ++mi) {
            for (int r = 0; r < 4; ++r) {
                int row = m0 + wm + mi * 16 + quad * 4 + r;
                float v = acc[mi][ni][r] + bv;
                if (GELU) v = gelu_exact(v);
                if (res) v += res[(size_t)row * N + col];
                out[(size_t)row * N + col] = (OutT)v;
            }
        }
    }
}

// ---------------- V transpose: qkv v-part [b][s][2048+h*64+d] -> vt[b][h][d][s] -----
__global__ __launch_bounds__(256) void transpose_v(const __bf16* __restrict__ qkv,
                                                   __bf16* __restrict__ vt) {
    __shared__ __bf16 tile[64][72];
    int b = blockIdx.z, h = blockIdx.y, s0 = blockIdx.x * 64;
    int t = threadIdx.x;
    int dl = (t & 7) * 8, sl = t >> 3;
    for (int p = 0; p < 2; ++p) {
        int s = sl + p * 32;
        bf16x8 val = *(const bf16x8*)(qkv + (size_t)(b * SEQ + s0 + s) * QKVS + 2048 + h * DK + dl);
        *(bf16x8*)&tile[s][dl] = val;
    }
    __syncthreads();
    int sl2 = (t & 7) * 8, d = t >> 3;
    for (int p = 0; p < 2; ++p) {
        int dd = d + p * 32;
        bf16x8 val;
        for (int j = 0; j < 8; ++j) val[j] = tile[sl2 + j][dd];
        *(bf16x8*)(vt + ((size_t)(b * NH + h) * DK + dd) * SEQ + s0 + sl2) = val;
    }
}

// ---------------- Flash attention, transposed-score layout --------------------------
// 1 wave = 16 q-rows, 128-key tiles. Scores via mfma(K,Q): row=key, col=query(fr)
// -> each lane owns one query's 32 scores: local reg-tree reductions + only 2
// chained shfls (xor 16,32) for max and sum. P packed b64 into per-wave LDS,
// read back as PV A-fragments. alpha/l broadcast to C-layout lanes via 4 shfls.
__global__ __launch_bounds__(256) void attn_kernel(const __bf16* __restrict__ qkv,
                                                   const __bf16* __restrict__ vt,
                                                   __bf16* __restrict__ ctx) {
    __shared__ __bf16 Plds[4][16][136];   // [wave][query][128 keys + 8 pad]
    int b = blockIdx.z, h = blockIdx.y;
    int wave = threadIdx.x >> 6, lane = threadIdx.x & 63;
    int q0 = blockIdx.x * 64 + wave * 16;
    int fr = lane & 15, quad = lane >> 4;
    const float scale = 0.125f;   // 1/sqrt(64)

    // Q B-frag: B[n=fr(query)][k=quad*8+j(d)]
    const __bf16* qp = qkv + (size_t)(b * SEQ + q0 + fr) * QKVS + h * DK + quad * 8;
    bf16x8 qf0 = *(const bf16x8*)qp;
    bf16x8 qf1 = *(const bf16x8*)(qp + 32);

    const __bf16* kbase = qkv + (size_t)b * SEQ * QKVS + 1024 + h * DK + quad * 8;
    const __bf16* vtbase = vt + (size_t)(b * NH + h) * DK * SEQ;

    floatx4 o[4] = {};                 // C layout: row=query quad*4+r, col=d ti*16+fr
    float m_i = -1e30f, l_i = 0.f;     // per query fr (replicated over quads)

    for (int k0 = 0; k0 < SEQ; k0 += 128) {
        // scores: s[f] covers keys k0+f*16+{quad*4+r}, query fr
        floatx4 s[8];
        for (int f = 0; f < 8; ++f) {
            const __bf16* kp = kbase + (size_t)(k0 + f * 16 + fr) * QKVS;
            bf16x8 kf0 = *(const bf16x8*)kp;
            bf16x8 kf1 = *(const bf16x8*)(kp + 32);
            floatx4 z = {0.f, 0.f, 0.f, 0.f};
            z = __builtin_amdgcn_mfma_f32_16x16x32_bf16(kf0, qf0, z, 0, 0, 0);
            s[f] = __builtin_amdgcn_mfma_f32_16x16x32_bf16(kf1, qf1, z, 0, 0, 0);
        }
        // online softmax for query fr: local tree + 2 chained shfls
        float mx = s[0][0];
        for (int f = 0; f < 8; ++f)
            for (int r = 0; r < 4; ++r) mx = fmaxf(mx, s[f][r]);
        mx *= scale;
        mx = fmaxf(mx, __shfl_xor(mx, 16));
        mx = fmaxf(mx, __shfl_xor(mx, 32));
        float mn = fmaxf(m_i, mx);
        float alpha = __expf(m_i - mn);
        m_i = mn;
        float rs = 0.f;
        for (int f = 0; f < 8; ++f) {
            bf16x4 pk;
            for (int r = 0; r < 4; ++r) {
                float p = __expf(s[f][r] * scale - mn);
                rs += p;
                pk[r] = (__bf16)p;
            }
            *(bf16x4*)&Plds[wave][fr][f * 16 + quad * 4] = pk;   // ds_write_b64
        }
        rs += __shfl_xor(rs, 16);
        rs += __shfl_xor(rs, 32);
        l_i = l_i * alpha + rs;
        // broadcast alpha to o-layout lanes (query quad*4+r held by lane quad*4+r)
        float aB[4];
        for (int r = 0; r < 4; ++r) aB[r] = __shfl(alpha, quad * 4 + r);
        for (int ti = 0; ti < 4; ++ti)
            for (int r = 0; r < 4; ++r) o[ti][r] *= aB[r];
        __threadfence_block();   // order wave-private LDS writes -> cross-lane reads
        // PV: A-frag P[m=fr(query)][k=key], B-frag vt[n=d][k=key]
        for (int c = 0; c < 4; ++c) {
            bf16x8 pa = *(const bf16x8*)&Plds[wave][fr][c * 32 + quad * 8];
            for (int ti = 0; ti < 4; ++ti) {
                const __bf16* vp = vtbase + (size_t)(ti * 16 + fr) * SEQ + k0 + c * 32 + quad * 8;
                bf16x8 vf = *(const bf16x8*)vp;
                o[ti] = __builtin_amdgcn_mfma_f32_16x16x32_bf16(pa, vf, o[ti], 0, 0, 0);
            }
        }
        __threadfence_block();   // reads done before next iteration's writes
    }
    float lB[4];
    for (int r = 0; r < 4; ++r) lB[r] = __shfl(l_i, quad * 4 + r);
    for (int ti = 0; ti < 4; ++ti)
        for (int r = 0; r < 4; ++r)
            ctx[(size_t)(b * SEQ + q0 + quad * 4 + r) * D_MODEL + h * DK + ti * 16 + fr] =
                (__bf16)(o[ti][r] / lB[r]);
}

// -----------------------------------------------------------------------------------
// Inputs fp32, output fp32. Workspace exactly 72 MiB:
//   [0,6M):   wqkvB (wq,wk,wv adjacent -> one [3072][1024] matrix)
//   [6,8M):   woB      [8,16M): w1B      [16,24M): w2B
//   [24,40M): h1 (dead after qkv-gemm) -> x1 fp32 trunk
//   [40,64M): qkv [4096][3072]  -> (dead after attn) ffh lower part
//   [64,72M): vt                -> (dead after attn) ffh upper part; ffh = [40,72M)
//   d_out:    ctx -> h2 -> final out
extern "C" void kernel_launch(void* const* d_in, const int* in_sizes, int n_in,
                              void* d_out, int out_size, void* d_ws, size_t ws_size,
                              hipStream_t stream) {
    const float* x   = (const float*)d_in[0];
    const float* wq  = (const float*)d_in[1];
    const float* bq  = (const float*)d_in[2];
    const float* wk  = (const float*)d_in[3];
    const float* bk  = (const float*)d_in[4];
    const float* wv  = (const float*)d_in[5];
    const float* bv  = (const float*)d_in[6];
    const float* wo  = (const float*)d_in[7];
    const float* bo  = (const float*)d_in[8];
    const float* w1  = (const float*)d_in[9];
    const float* b1  = (const float*)d_in[10];
    const float* w2  = (const float*)d_in[11];
    const float* b2  = (const float*)d_in[12];
    const float* g1  = (const float*)d_in[13];
    const float* be1 = (const float*)d_in[14];
    const float* g2  = (const float*)d_in[15];
    const float* be2 = (const float*)d_in[16];
    float* out = (float*)d_out;

    char* ws = (char*)d_ws;
    const size_t MB = 1024 * 1024;
    __bf16* wqkvB = (__bf16*)(ws);                 // [0,6M)
    __bf16* woB   = (__bf16*)(ws + 6 * MB);
    __bf16* w1B   = (__bf16*)(ws + 8 * MB);
    __bf16* w2B   = (__bf16*)(ws + 16 * MB);
    __bf16* h1    = (__bf16*)(ws + 24 * MB);       // dead after qkv-gemm
    float*  x1    = (float*)(ws + 24 * MB);        // fp32 trunk [24,40M)
    __bf16* qkv   = (__bf16*)(ws + 40 * MB);       // [40,64M)
    __bf16* vt    = (__bf16*)(ws + 64 * MB);       // [64,72M)
    __bf16* ffh   = (__bf16*)(ws + 40 * MB);       // [40,72M) after qkv+vt die
    __bf16* ctx   = (__bf16*)d_out;                // d_out scratch [0,8M)
    __bf16* h2    = (__bf16*)d_out;                // d_out scratch (after ctx dies)

    const int NDD = D_MODEL * D_MODEL;   // 1M
    const int NDF = D_MODEL * DFF;       // 4M
    cast_f32_bf16<<<NDD / 2048, 256, 0, stream>>>(wq, wqkvB, NDD);
    cast_f32_bf16<<<NDD / 2048, 256, 0, stream>>>(wk, wqkvB + NDD, NDD);
    cast_f32_bf16<<<NDD / 2048, 256, 0, stream>>>(wv, wqkvB + 2 * NDD, NDD);
    cast_f32_bf16<<<NDD / 2048, 256, 0, stream>>>(wo, woB, NDD);
    cast_f32_bf16<<<NDF / 2048, 256, 0, stream>>>(w1, w1B, NDF);
    cast_f32_bf16<<<NDF / 2048, 256, 0, stream>>>(w2, w2B, NDF);

    dim3 gQKV(QKVS / 128, NTOK / 128);    // (24, 32) = 768 blocks
    dim3 gD(D_MODEL / 128, NTOK / 128);   // (8, 32)  = 256 blocks
    dim3 gF(DFF / 128, NTOK / 128);       // (32, 32) = 1024 blocks
    dim3 gAttn(SEQ / 64, NH, BATCH);      // (32, 16, 2)

    // 1. h1 = LN(x, g1, be1)
    ln_kernel<<<NTOK, 64, 0, stream>>>(x, g1, be1, h1);
    // 2. qkv = h1 @ [wq;wk;wv]^T + [bq;bk;bv]   (fused, N=3072)
    gemm_bt<__bf16, false, true><<<gQKV, 256, 0, stream>>>(h1, wqkvB, bq, bk, bv, nullptr, qkv, NTOK, QKVS, D_MODEL);
    // 3. vt = transpose(v) per head
    transpose_v<<<gAttn, 256, 0, stream>>>(qkv, vt);
    // 4. ctx = softmax(q k^T / sqrt(dk)) v   (writes d_out)
    attn_kernel<<<gAttn, 256, 0, stream>>>(qkv, vt, ctx);
    // 5. x1 = x + ctx @ wo^T + bo   (fp32 trunk; h1 dead)
    gemm_bt<float, false, false><<<gD, 256, 0, stream>>>(ctx, woB, bo, bo, bo, x, x1, NTOK, D_MODEL, D_MODEL);
    // 6. h2 = LN(x1, g2, be2)   (overwrites ctx in d_out)
    ln_kernel<<<NTOK, 64, 0, stream>>>(x1, g2, be2, h2);
    // 7. ffh = gelu(h2 @ w1^T + b1)   (full 32 MiB over qkv+vt)
    gemm_bt<__bf16, true, false><<<gF, 256, 0, stream>>>(h2, w1B, b1, b1, b1, nullptr, ffh, NTOK, DFF, D_MODEL);
    // 8. out = x1 + ffh @ w2^T + b2   (overwrites h2/d_out; h2 fully consumed in 7)
    gemm_bt<float, false, false><<<gD, 256, 0, stream>>>(ffh, w2B, b2, b2, b2, x1, out, NTOK, D_MODEL, DFF);
}